// Round 5
// baseline (395.753 us; speedup 1.0000x reference)
//
#include <hip/hip_runtime.h>
#include <hip/hip_bf16.h>
#include <hip/hip_fp16.h>

#define NN    50000
#define NE    800000
#define ETOT  (NE + NN)
#define D     128
#define NB    ((NN + 255) / 256)   // scan blocks

__device__ __forceinline__ float gelu_tanh(float x) {
    float x3 = x * x * x;
    float t  = tanhf(0.7978845608028654f * (x + 0.044715f * x3));
    return 0.5f * x * (1.0f + t);
}

__device__ __forceinline__ float rdlane(float v, int l) {
    return __int_as_float(__builtin_amdgcn_readlane(__float_as_int(v), l));
}

// ---------------- CSR build ----------------

__global__ void count_k(const int* __restrict__ dstarr, int* __restrict__ counts) {
    int e = blockIdx.x * blockDim.x + threadIdx.x;
    if (e >= ETOT) return;
    int d = (e < NE) ? dstarr[e] : (e - NE);
    atomicAdd(&counts[d], 1);
}

__global__ void scan1_k(const int* __restrict__ counts, int* __restrict__ blk_sums) {
    __shared__ int sm[4];
    int i = blockIdx.x * 256 + threadIdx.x;
    int v = (i < NN) ? counts[i] : 0;
    #pragma unroll
    for (int o = 32; o; o >>= 1) v += __shfl_xor(v, o);
    if ((threadIdx.x & 63) == 0) sm[threadIdx.x >> 6] = v;
    __syncthreads();
    if (threadIdx.x == 0) blk_sums[blockIdx.x] = sm[0] + sm[1] + sm[2] + sm[3];
}

__global__ void scan2_k(const int* __restrict__ blk_sums, int* __restrict__ blk_offs,
                        int* __restrict__ row_ptr) {
    if (threadIdx.x == 0 && blockIdx.x == 0) {
        int acc = 0;
        for (int b = 0; b < NB; ++b) { blk_offs[b] = acc; acc += blk_sums[b]; }
        row_ptr[NN] = acc;
    }
}

__global__ void scan3_k(const int* __restrict__ counts, const int* __restrict__ blk_offs,
                        int* __restrict__ row_ptr, int* __restrict__ write_ptr) {
    __shared__ int s[256];
    int t = threadIdx.x;
    int i = blockIdx.x * 256 + t;
    int v = (i < NN) ? counts[i] : 0;
    s[t] = v;
    __syncthreads();
    for (int off = 1; off < 256; off <<= 1) {
        int x = (t >= off) ? s[t - off] : 0;
        __syncthreads();
        s[t] += x;
        __syncthreads();
    }
    int excl = s[t] - v + blk_offs[blockIdx.x];
    if (i < NN) { row_ptr[i] = excl; write_ptr[i] = excl; }
}

__global__ void scatter_k(const int* __restrict__ srcarr, const int* __restrict__ dstarr,
                          int* __restrict__ write_ptr, int* __restrict__ srcs) {
    int e = blockIdx.x * blockDim.x + threadIdx.x;
    if (e >= ETOT) return;
    int d, s;
    if (e < NE) { d = dstarr[e]; s = srcarr[e]; }
    else        { d = e - NE;    s = e - NE; }
    int pos = atomicAdd(&write_ptr[d], 1);
    srcs[pos] = s;
}

// ------------- wasd: per layer, was[k]=sum_c W[k][c]*as[c], wad likewise -------------

__global__ void wasd_k(const float* __restrict__ W, const float* __restrict__ asrc,
                       const float* __restrict__ adst, float* __restrict__ wasd) {
    int l = blockIdx.x;
    int t = threadIdx.x;
    int k = t & 127, which = t >> 7;
    const float* wr = W + (size_t)l * D * D + (size_t)k * D;
    const float* av = (which ? adst : asrc) + (size_t)l * D;
    float s = 0.f;
    #pragma unroll 4
    for (int c = 0; c < D; ++c) s += wr[c] * av[c];
    wasd[l * 256 + which * 128 + k] = s;
}

// ------------- gemm2: full-W-in-LDS, barrier-free wave-per-8-rows fp32 GEMM -------------
// XP = A @ W; fused alpha_s/d = A @ wasd. 256 thr = 4 waves x 8 rows -> 32 rows/block.

template <typename OutT>
__global__ __launch_bounds__(256) void gemm2_k(
        const float* __restrict__ A, const float* __restrict__ W,
        const float* __restrict__ wasd,
        OutT* __restrict__ XP, float* __restrict__ alpha_s, float* __restrict__ alpha_d) {
    __shared__ float Ws[D * D];          // 64 KB: W[k][c] row-major

    int t = threadIdx.x;
    // stage full W (coalesced float4, linear LDS)
    #pragma unroll
    for (int i = 0; i < 16; ++i)
        ((float4*)Ws)[t + i * 256] = ((const float4*)W)[t + i * 256];
    __syncthreads();

    int lane = t & 63, wv = t >> 6;
    int row0 = blockIdx.x * 32 + wv * 8;
    int rsub = lane >> 5;                // which row of the pair this lane loads
    int kq   = (lane & 31) * 4;          // k-offset of this lane's float4

    // load 8 A rows (2 per j), lane holds k-slice [kq, kq+3]
    float4 a[4];
    #pragma unroll
    for (int j = 0; j < 4; ++j) {
        int r = row0 + j * 2 + rsub;
        int rc = r < NN ? r : NN - 1;
        a[j] = *(const float4*)(A + (size_t)rc * D + kq);
    }

    // fused alphas: per-lane partial dot with wasd, reduce over 32-lane half
    {
        float4 ws4 = *(const float4*)(wasd + kq);
        float4 wd4 = *(const float4*)(wasd + 128 + kq);
        #pragma unroll
        for (int j = 0; j < 4; ++j) {
            float ps = a[j].x*ws4.x + a[j].y*ws4.y + a[j].z*ws4.z + a[j].w*ws4.w;
            float pd = a[j].x*wd4.x + a[j].y*wd4.y + a[j].z*wd4.z + a[j].w*wd4.w;
            #pragma unroll
            for (int o = 16; o; o >>= 1) {
                ps += __shfl_xor(ps, o);
                pd += __shfl_xor(pd, o);
            }
            if ((lane & 31) == 0) {
                int r = row0 + j * 2 + rsub;
                if (r < NN) { alpha_s[r] = ps; alpha_d[r] = pd; }
            }
        }
    }

    // main loop: acc[r] = row row0+r, cols (lane, lane+64)
    float2 acc[8] = {{0,0},{0,0},{0,0},{0,0},{0,0},{0,0},{0,0},{0,0}};
    for (int kc = 0; kc < 32; ++kc) {
        int kb = kc * 4;
        float w0[4], w1[4];
        #pragma unroll
        for (int i = 0; i < 4; ++i) {
            w0[i] = Ws[(kb + i) * D + lane];
            w1[i] = Ws[(kb + i) * D + 64 + lane];
        }
        #pragma unroll
        for (int j = 0; j < 4; ++j) {
            // A[row0+2j+h][kb+i] held by lane h*32+kc, element i of a[j]
            float e0, e1;
            #define DO_K(i, EL) \
                e0 = rdlane(a[j].EL, kc); \
                e1 = rdlane(a[j].EL, 32 + kc); \
                acc[2*j].x   = fmaf(e0, w0[i], acc[2*j].x); \
                acc[2*j].y   = fmaf(e0, w1[i], acc[2*j].y); \
                acc[2*j+1].x = fmaf(e1, w0[i], acc[2*j+1].x); \
                acc[2*j+1].y = fmaf(e1, w1[i], acc[2*j+1].y);
            DO_K(0, x) DO_K(1, y) DO_K(2, z) DO_K(3, w)
            #undef DO_K
        }
    }

    // epilogue
    #pragma unroll
    for (int r = 0; r < 8; ++r) {
        int row = row0 + r;
        if (row < NN) {
            if constexpr (sizeof(OutT) == 4) {
                float* o = (float*)XP + (size_t)row * D;
                o[lane]      = acc[r].x;
                o[64 + lane] = acc[r].y;
            } else {
                __half* o = (__half*)XP + (size_t)row * D;
                o[lane]      = __float2half_rn(acc[r].x);
                o[64 + lane] = __float2half_rn(acc[r].y);
            }
        }
    }
}

// ---------------- fp16 aggregation: wave per dst node, quarter-wave per edge row ----------------

__global__ __launch_bounds__(256) void agg_half_k(
        const int* __restrict__ row_ptr, const int* __restrict__ srcs,
        const float* __restrict__ alpha_s, const float* __restrict__ alpha_d,
        const __half* __restrict__ XPH, const float* __restrict__ bias,
        float* __restrict__ OUT) {
    int n = (blockIdx.x * blockDim.x + threadIdx.x) >> 6;
    int lane = threadIdx.x & 63;
    int beg = row_ptr[n], end = row_ptr[n + 1], deg = end - beg;
    float ad = alpha_d[n];

    if (deg <= 64) {
        int sreg = 0;
        float e = -3.4e38f;
        if (lane < deg) {
            sreg = srcs[beg + lane];
            float v = alpha_s[sreg] + ad;
            e = v > 0.f ? v : 0.2f * v;
        }
        float m = e;
        #pragma unroll
        for (int o = 32; o; o >>= 1) m = fmaxf(m, __shfl_xor(m, o));
        float w = (lane < deg) ? __expf(e - m) : 0.f;
        float denom = w;
        #pragma unroll
        for (int o = 32; o; o >>= 1) denom += __shfl_xor(denom, o);

        int qw = lane >> 4, q = lane & 15;
        float acc[8] = {0,0,0,0,0,0,0,0};
        int dgr = (deg + 3) & ~3;
        const uint4* base = (const uint4*)XPH;
        int j = 0;
        for (; j + 8 <= dgr; j += 8) {
            int e0 = j + qw, e1 = j + 4 + qw;
            int   s0 = __shfl(sreg, e0); float w0 = __shfl(w, e0);
            int   s1 = __shfl(sreg, e1); float w1 = __shfl(w, e1);
            uint4 u0 = base[(size_t)s0 * 16 + q];
            uint4 u1 = base[(size_t)s1 * 16 + q];
            {
                union { uint4 u; __half2 h[4]; } U; U.u = u0;
                float2 f0 = __half22float2(U.h[0]);
                float2 f1 = __half22float2(U.h[1]);
                float2 f2 = __half22float2(U.h[2]);
                float2 f3 = __half22float2(U.h[3]);
                acc[0] += w0*f0.x; acc[1] += w0*f0.y; acc[2] += w0*f1.x; acc[3] += w0*f1.y;
                acc[4] += w0*f2.x; acc[5] += w0*f2.y; acc[6] += w0*f3.x; acc[7] += w0*f3.y;
            }
            {
                union { uint4 u; __half2 h[4]; } U; U.u = u1;
                float2 f0 = __half22float2(U.h[0]);
                float2 f1 = __half22float2(U.h[1]);
                float2 f2 = __half22float2(U.h[2]);
                float2 f3 = __half22float2(U.h[3]);
                acc[0] += w1*f0.x; acc[1] += w1*f0.y; acc[2] += w1*f1.x; acc[3] += w1*f1.y;
                acc[4] += w1*f2.x; acc[5] += w1*f2.y; acc[6] += w1*f3.x; acc[7] += w1*f3.y;
            }
        }
        for (; j < dgr; j += 4) {
            int e0 = j + qw;
            int s0 = __shfl(sreg, e0); float w0 = __shfl(w, e0);
            uint4 u0 = base[(size_t)s0 * 16 + q];
            union { uint4 u; __half2 h[4]; } U; U.u = u0;
            float2 f0 = __half22float2(U.h[0]);
            float2 f1 = __half22float2(U.h[1]);
            float2 f2 = __half22float2(U.h[2]);
            float2 f3 = __half22float2(U.h[3]);
            acc[0] += w0*f0.x; acc[1] += w0*f0.y; acc[2] += w0*f1.x; acc[3] += w0*f1.y;
            acc[4] += w0*f2.x; acc[5] += w0*f2.y; acc[6] += w0*f3.x; acc[7] += w0*f3.y;
        }
        #pragma unroll
        for (int f = 0; f < 8; ++f) {
            acc[f] += __shfl_xor(acc[f], 16);
            acc[f] += __shfl_xor(acc[f], 32);
        }
        if (lane < 16) {
            float inv = 1.f / (denom + 1e-16f);
            const float4* b4 = (const float4*)bias;
            float4 ba = b4[q * 2], bb = b4[q * 2 + 1];
            float4 oA, oB;
            oA.x = gelu_tanh(acc[0]*inv + ba.x); oA.y = gelu_tanh(acc[1]*inv + ba.y);
            oA.z = gelu_tanh(acc[2]*inv + ba.z); oA.w = gelu_tanh(acc[3]*inv + ba.w);
            oB.x = gelu_tanh(acc[4]*inv + bb.x); oB.y = gelu_tanh(acc[5]*inv + bb.y);
            oB.z = gelu_tanh(acc[6]*inv + bb.z); oB.w = gelu_tanh(acc[7]*inv + bb.w);
            float4* o = (float4*)(OUT + (size_t)n * D + q * 8);
            o[0] = oA; o[1] = oB;
        }
    } else {
        float m = -3.4e38f;
        for (int i = beg + lane; i < end; i += 64) {
            int s = srcs[i];
            float v = alpha_s[s] + ad; v = v > 0.f ? v : 0.2f * v;
            m = fmaxf(m, v);
        }
        #pragma unroll
        for (int o = 32; o; o >>= 1) m = fmaxf(m, __shfl_xor(m, o));
        float denom = 0.f;
        for (int i = beg + lane; i < end; i += 64) {
            int s = srcs[i];
            float v = alpha_s[s] + ad; v = v > 0.f ? v : 0.2f * v;
            denom += __expf(v - m);
        }
        #pragma unroll
        for (int o = 32; o; o >>= 1) denom += __shfl_xor(denom, o);
        float2 acc = {0.f, 0.f};
        for (int i = beg; i < end; ++i) {
            int s = srcs[i];
            float v = alpha_s[s] + ad; v = v > 0.f ? v : 0.2f * v;
            float wgt = __expf(v - m);
            union { unsigned int x; __half2 h; } U;
            U.x = ((const unsigned int*)(XPH + (size_t)s * D))[lane];
            float2 f = __half22float2(U.h);
            acc.x += wgt * f.x; acc.y += wgt * f.y;
        }
        float inv = 1.f / (denom + 1e-16f);
        float2 b2 = ((const float2*)bias)[lane];
        float r0 = gelu_tanh(acc.x * inv + b2.x);
        float r1 = gelu_tanh(acc.y * inv + b2.y);
        ((float2*)(OUT + (size_t)n * D))[lane] = make_float2(r0, r1);
    }
}

// ---------------- fp32 aggregation (layer 3) ----------------

__global__ __launch_bounds__(256) void agg_k(
        const int* __restrict__ row_ptr, const int* __restrict__ srcs,
        const float* __restrict__ alpha_s, const float* __restrict__ alpha_d,
        const float* __restrict__ XP, const float* __restrict__ bias,
        float* __restrict__ OUT, int apply_gelu) {
    int n = (blockIdx.x * blockDim.x + threadIdx.x) >> 6;
    int lane = threadIdx.x & 63;
    int beg = row_ptr[n], end = row_ptr[n + 1], deg = end - beg;
    float ad = alpha_d[n];

    if (deg <= 64) {
        int sreg = 0;
        float e = -3.4e38f;
        if (lane < deg) {
            sreg = srcs[beg + lane];
            float v = alpha_s[sreg] + ad;
            e = v > 0.f ? v : 0.2f * v;
        }
        float m = e;
        #pragma unroll
        for (int o = 32; o; o >>= 1) m = fmaxf(m, __shfl_xor(m, o));
        float w = (lane < deg) ? __expf(e - m) : 0.f;
        float denom = w;
        #pragma unroll
        for (int o = 32; o; o >>= 1) denom += __shfl_xor(denom, o);

        int half = lane >> 5, q = lane & 31;
        float4 acc0 = {0,0,0,0}, acc1 = {0,0,0,0};
        int j = 0;
        for (; j + 4 <= deg; j += 4) {
            int   s0 = __shfl(sreg, j + half);
            float w0 = __shfl(w,    j + half);
            int   s1 = __shfl(sreg, j + 2 + half);
            float w1 = __shfl(w,    j + 2 + half);
            float4 x0 = ((const float4*)(XP + (size_t)s0 * D))[q];
            float4 x1 = ((const float4*)(XP + (size_t)s1 * D))[q];
            acc0.x += w0 * x0.x; acc0.y += w0 * x0.y;
            acc0.z += w0 * x0.z; acc0.w += w0 * x0.w;
            acc1.x += w1 * x1.x; acc1.y += w1 * x1.y;
            acc1.z += w1 * x1.z; acc1.w += w1 * x1.w;
        }
        for (; j < deg; j += 2) {
            int ej = j + half;
            int   s0 = __shfl(sreg, ej < 63 ? ej : 63);
            float w0 = __shfl(w,    ej < 63 ? ej : 63);
            if (ej < deg) {
                float4 x0 = ((const float4*)(XP + (size_t)s0 * D))[q];
                acc0.x += w0 * x0.x; acc0.y += w0 * x0.y;
                acc0.z += w0 * x0.z; acc0.w += w0 * x0.w;
            }
        }
        float4 tot;
        tot.x = acc0.x + acc1.x; tot.y = acc0.y + acc1.y;
        tot.z = acc0.z + acc1.z; tot.w = acc0.w + acc1.w;
        tot.x += __shfl_xor(tot.x, 32);
        tot.y += __shfl_xor(tot.y, 32);
        tot.z += __shfl_xor(tot.z, 32);
        tot.w += __shfl_xor(tot.w, 32);

        if (half == 0) {
            float inv = 1.f / (denom + 1e-16f);
            float4 b4 = ((const float4*)bias)[q];
            float r0 = tot.x * inv + b4.x;
            float r1 = tot.y * inv + b4.y;
            float r2 = tot.z * inv + b4.z;
            float r3 = tot.w * inv + b4.w;
            if (apply_gelu) {
                r0 = gelu_tanh(r0); r1 = gelu_tanh(r1);
                r2 = gelu_tanh(r2); r3 = gelu_tanh(r3);
            }
            ((float4*)(OUT + (size_t)n * D))[q] = make_float4(r0, r1, r2, r3);
        }
    } else {
        float m = -3.4e38f;
        for (int i = beg + lane; i < end; i += 64) {
            int s = srcs[i];
            float v = alpha_s[s] + ad;
            v = v > 0.f ? v : 0.2f * v;
            m = fmaxf(m, v);
        }
        #pragma unroll
        for (int o = 32; o; o >>= 1) m = fmaxf(m, __shfl_xor(m, o));
        float denom = 0.f;
        for (int i = beg + lane; i < end; i += 64) {
            int s = srcs[i];
            float v = alpha_s[s] + ad;
            v = v > 0.f ? v : 0.2f * v;
            denom += __expf(v - m);
        }
        #pragma unroll
        for (int o = 32; o; o >>= 1) denom += __shfl_xor(denom, o);
        float2 acc = {0.f, 0.f};
        for (int i = beg; i < end; ++i) {
            int s = srcs[i];
            float v = alpha_s[s] + ad;
            v = v > 0.f ? v : 0.2f * v;
            float wgt = __expf(v - m);
            float2 xv = ((const float2*)(XP + (size_t)s * D))[lane];
            acc.x += wgt * xv.x;
            acc.y += wgt * xv.y;
        }
        float inv = 1.f / (denom + 1e-16f);
        float2 b2 = ((const float2*)bias)[lane];
        float r0 = acc.x * inv + b2.x;
        float r1 = acc.y * inv + b2.y;
        if (apply_gelu) { r0 = gelu_tanh(r0); r1 = gelu_tanh(r1); }
        ((float2*)(OUT + (size_t)n * D))[lane] = make_float2(r0, r1);
    }
}

// ---------------- launch ----------------

extern "C" void kernel_launch(void* const* d_in, const int* in_sizes, int n_in,
                              void* d_out, int out_size, void* d_ws, size_t ws_size,
                              hipStream_t stream) {
    const float* x    = (const float*)d_in[0];
    const int*   ei   = (const int*)d_in[1];
    const float* W    = (const float*)d_in[2];
    const float* asrc = (const float*)d_in[3];
    const float* adst = (const float*)d_in[4];
    const float* bias = (const float*)d_in[5];
    float* out = (float*)d_out;

    const int* src_arr = ei;
    const int* dst_arr = ei + NE;

    char* ws = (char*)d_ws;
    size_t off = 0;
    auto alloc = [&](size_t bytes) { char* p = ws + off; off += (bytes + 255) & ~(size_t)255; return p; };
    float*  xp      = (float*)alloc((size_t)NN * D * sizeof(float));
    __half* xph     = (__half*)alloc((size_t)NN * D * sizeof(__half));
    float*  hbuf    = (float*)alloc((size_t)NN * D * sizeof(float));
    float*  alpha_s = (float*)alloc(NN * sizeof(float));
    float*  alpha_d = (float*)alloc(NN * sizeof(float));
    float*  wasd    = (float*)alloc(3 * 256 * sizeof(float));
    int* counts    = (int*)alloc(NN * sizeof(int));
    int* row_ptr   = (int*)alloc((NN + 1) * sizeof(int));
    int* write_ptr = (int*)alloc(NN * sizeof(int));
    int* blk_sums  = (int*)alloc(NB * sizeof(int));
    int* blk_offs  = (int*)alloc(NB * sizeof(int));
    int* srcs      = (int*)alloc((size_t)ETOT * sizeof(int));
    (void)ws_size; (void)in_sizes; (void)n_in; (void)out_size;

    hipMemsetAsync(counts, 0, NN * sizeof(int), stream);
    int eb = (ETOT + 255) / 256;
    count_k<<<eb, 256, 0, stream>>>(dst_arr, counts);
    scan1_k<<<NB, 256, 0, stream>>>(counts, blk_sums);
    scan2_k<<<1, 64, 0, stream>>>(blk_sums, blk_offs, row_ptr);
    scan3_k<<<NB, 256, 0, stream>>>(counts, blk_offs, row_ptr, write_ptr);
    scatter_k<<<eb, 256, 0, stream>>>(src_arr, dst_arr, write_ptr, srcs);

    wasd_k<<<3, 256, 0, stream>>>(W, asrc, adst, wasd);

    int gemm_blocks = (NN + 31) / 32;   // 1563
    int agg_blocks  = NN / 4;           // 12500

    // layer 0: fp16 xp
    gemm2_k<__half><<<gemm_blocks, 256, 0, stream>>>(x, W, wasd, xph, alpha_s, alpha_d);
    agg_half_k<<<agg_blocks, 256, 0, stream>>>(row_ptr, srcs, alpha_s, alpha_d, xph,
                                               bias, hbuf);
    // layer 1: fp16 xp
    gemm2_k<__half><<<gemm_blocks, 256, 0, stream>>>(hbuf, W + (size_t)1 * D * D,
                                                     wasd + 256, xph, alpha_s, alpha_d);
    agg_half_k<<<agg_blocks, 256, 0, stream>>>(row_ptr, srcs, alpha_s, alpha_d, xph,
                                               bias + D, out);
    // layer 2: fp32 xp (output precision)
    gemm2_k<float><<<gemm_blocks, 256, 0, stream>>>(out, W + (size_t)2 * D * D,
                                                    wasd + 512, xp, alpha_s, alpha_d);
    agg_k<<<agg_blocks, 256, 0, stream>>>(row_ptr, srcs, alpha_s, alpha_d, xp,
                                          bias + 2 * D, out, 0);
}